// Round 3
// baseline (300.168 us; speedup 1.0000x reference)
//
#include <hip/hip_runtime.h>
#include <math.h>

typedef _Float16 f16x8 __attribute__((ext_vector_type(8)));
typedef float f32x4 __attribute__((ext_vector_type(4)));

// Problem constants
#define NROWS 32768   // 8*4096 input rows
#define KEMB  8192    // codebook entries
// DIM = 64

#define DECAYF 0.99f
#define OMDF   0.01f

// d_out layout (floats), reference return order
#define OUT_Q    0          // quantized, 2097152
#define OUT_LOSS 2097152    // vq_loss, 1
#define OUT_IDX  2097153    // idx (as float), 32768
#define OUT_PERP 2129921    // perplexity, 1
#define OUT_NW   2129922    // new_weight, 524288
#define OUT_NCC  2654210    // new_cc, 8192
#define OUT_NWS  2662402    // new_ws, 524288

// d_ws layout (4-byte units)
#define WS_N      0
#define WS_ENT    1
#define WS_CTR    2                    // argmin completion counter (int)
#define WS_CTR2   3                    // update_quant completion counter (int)
#define WS_COUNTS 4                    // 8192 floats (argmin atomics; reused as loss partials)
#define WS_EMB    8196                 // 524288 floats (atomic)
#define WS_IDX    532484               // 32768 ints
#define WS_W2H    565252               // 8192 floats (= ||w||^2 / 2)
#define WS_WFRAG  573444               // 524288 f32 units = 2 MB f16 frag image
#define WS_ZERO_UNITS 532484           // scalars+ctrs+counts+emb

__device__ __forceinline__ float sq_rn(float v) { return __fmul_rn(v, v); }

// numpy pairwise_sum order for 64 contiguous squared values
__device__ __forceinline__ float npsumsq64(const float* vbuf) {
  float a[8];
#pragma unroll
  for (int j = 0; j < 8; ++j) a[j] = sq_rn(vbuf[j]);
#pragma unroll
  for (int m = 1; m < 8; ++m)
#pragma unroll
    for (int j = 0; j < 8; ++j) a[j] = __fadd_rn(a[j], sq_rn(vbuf[m*8 + j]));
  return __fadd_rn(__fadd_rn(__fadd_rn(a[0],a[1]), __fadd_rn(a[2],a[3])),
                   __fadd_rn(__fadd_rn(a[4],a[5]), __fadd_rn(a[6],a[7])));
}

// split a float into (hi, lo) fp16 pair; hi+lo reproduces x to ~22 bits
__device__ __forceinline__ void split_f16(float x, _Float16& hi, _Float16& lo) {
  hi = (_Float16)x;
  float r = __fsub_rn(x, (float)hi);   // exact (Sterbenz)
  lo = (_Float16)r;
}

// prep: zero the atomic regions (replaces hipMemsetAsync), w2h[k] = 0.5*||w_k||^2
// (numpy order), W -> fragment-image f16 hi/lo.
// Image layout: frag(panel P, s, lane l) at wf[((P*4+s)*64+l)*8 .. +8];
// s=0,1 hi (K 0..31 / 32..63), s=2,3 lo. A per-lane dwordx4 load IS an MFMA frag.
__global__ __launch_bounds__(256) void prep_kernel(const float* __restrict__ wg,
                                                   float* __restrict__ ws) {
  const int tid = blockIdx.x * 256 + threadIdx.x;
  // grid-stride zero of scalars+ctrs+counts+emb (288*256 = 73728 threads)
#pragma unroll
  for (int z = tid; z < WS_ZERO_UNITS; z += 73728) ws[z] = 0.0f;

  if (tid < KEMB) {
    const float* src = wg + (size_t)tid * 64;
    float vbuf[64];
#pragma unroll
    for (int f = 0; f < 16; ++f) {
      float4 v = *(const float4*)(src + f*4);
      vbuf[f*4+0]=v.x; vbuf[f*4+1]=v.y; vbuf[f*4+2]=v.z; vbuf[f*4+3]=v.w;
    }
    ws[WS_W2H + tid] = __fmul_rn(0.5f, npsumsq64(vbuf));
  } else if (tid < KEMB + 65536) {
    const int u = tid - KEMB;            // granule: code K, dims g*8..g*8+7
    const int K = u >> 3, g = u & 7;
    const int n = K & 15, P = K >> 4;    // global panel 0..511
    const int slot = (g&3)*16 + n, shi = g >> 2;
    const float* src = wg + (size_t)K*64 + g*8;
    float4 v0 = *(const float4*)src, v1 = *(const float4*)(src + 4);
    float vv[8] = {v0.x,v0.y,v0.z,v0.w,v1.x,v1.y,v1.z,v1.w};
    f16x8 hi, lo;
#pragma unroll
    for (int j = 0; j < 8; ++j) { _Float16 h, l; split_f16(vv[j], h, l); hi[j]=h; lo[j]=l; }
    _Float16* wf = (_Float16*)(ws + WS_WFRAG);
    *(f16x8*)&wf[((size_t)(P*4 + shi)*64 + slot)*8]     = hi;
    *(f16x8*)&wf[((size_t)(P*4 + 2 + shi)*64 + slot)*8] = lo;
  }
}

// one 16-code-panel MFMA cluster into ACC (C-in = cw = 0.5||w||^2, A = W frags,
// B = resident negated X frags) — distances bit-identical to prior versions.
#define MFMA_CLUSTER(ACC)                                                                     \
  __builtin_amdgcn_s_setprio(1);                                                              \
  _Pragma("unroll")                                                                           \
  for (int bt = 0; bt < 4; ++bt) ACC[bt] = __builtin_amdgcn_mfma_f32_16x16x32_f16(wh0, b[bt][0], cw,      0,0,0); \
  _Pragma("unroll")                                                                           \
  for (int bt = 0; bt < 4; ++bt) ACC[bt] = __builtin_amdgcn_mfma_f32_16x16x32_f16(wh1, b[bt][1], ACC[bt], 0,0,0); \
  _Pragma("unroll")                                                                           \
  for (int bt = 0; bt < 4; ++bt) ACC[bt] = __builtin_amdgcn_mfma_f32_16x16x32_f16(wh0, b[bt][2], ACC[bt], 0,0,0); \
  _Pragma("unroll")                                                                           \
  for (int bt = 0; bt < 4; ++bt) ACC[bt] = __builtin_amdgcn_mfma_f32_16x16x32_f16(wh1, b[bt][3], ACC[bt], 0,0,0); \
  _Pragma("unroll")                                                                           \
  for (int bt = 0; bt < 4; ++bt) ACC[bt] = __builtin_amdgcn_mfma_f32_16x16x32_f16(wl0, b[bt][0], ACC[bt], 0,0,0); \
  _Pragma("unroll")                                                                           \
  for (int bt = 0; bt < 4; ++bt) ACC[bt] = __builtin_amdgcn_mfma_f32_16x16x32_f16(wl1, b[bt][1], ACC[bt], 0,0,0); \
  __builtin_amdgcn_s_setprio(0);

#define LOADNEXT()                                  \
  wh0 = *(const f16x8*)(wp);                        \
  wh1 = *(const f16x8*)(wp + 512);                  \
  wl0 = *(const f16x8*)(wp + 1024);                 \
  wl1 = *(const f16x8*)(wp + 1536);                 \
  cw  = *(const f32x4*)(cp);                        \
  wp += 16384; cp += 128;

// deferred tournament: runs on the PREVIOUS panel's acc (no dependency on the
// MFMA cluster just issued) -> VALU overlaps matrix-pipe work.
#define TOURN(ACC, C0)                                                       \
  _Pragma("unroll")                                                          \
  for (int bt = 0; bt < 4; ++bt) {                                           \
    const float d0 = ACC[bt][0], d1 = ACC[bt][1], d2 = ACC[bt][2], d3 = ACC[bt][3]; \
    const float pm = fminf(fminf(d0, d1), fminf(d2, d3));                    \
    int koff = 3;                                                            \
    if (d2 == pm) koff = 2;                                                  \
    if (d1 == pm) koff = 1;                                                  \
    if (d0 == pm) koff = 0;                                                  \
    if (pm < bestd[bt]) { bestd[bt] = pm; bestk[bt] = (C0) + koff; }         \
  }

// argmin v9: 256 blocks x 1024 threads (16 waves = rg2 x cg8), 128 rows/block.
// waves_per_eu(4,4) + LDS pad >80KB force the allocator to target 4 waves/SIMD
// (= the grid-limited occupancy) -> 128-VGPR budget, b-frags stay resident.
// accA/accB 2-deep pipeline defers each panel's tournament under the next
// panel's MFMA cluster. Stats (new_cc, n, entropy) fused via last-block.
__global__ __attribute__((amdgpu_flat_work_group_size(1024,1024), amdgpu_waves_per_eu(4,4)))
void argmin_kernel(const float* __restrict__ xg, const float* __restrict__ cc,
                   float* __restrict__ out, float* __restrict__ ws) {
  __shared__ __align__(16) _Float16 xp[8*4*64*8];   // 32 KB, X frags (negated)
  __shared__ float md[128*8];
  __shared__ int   mk[128*8];
  __shared__ int   bkL[128];
  __shared__ float s1[16], s2[16];
  __shared__ int   amLast;
  __shared__ float ldspad[10240];   // 40 KB occupancy shaping (never touched)

  const int t    = threadIdx.x;
  const int lane = t & 63, wv = t >> 6;     // wv 0..15
  const int quad = lane >> 4, n16 = lane & 15;
  const int rg = wv >> 3, cg = wv & 7;      // rg 0..1 (row half), cg 0..7 (code slice)
  const int row0 = blockIdx.x * 128;
  const _Float16* __restrict__ wfrag = (const _Float16*)(ws + WS_WFRAG);
  const float* __restrict__ w2hg = ws + WS_W2H;

  // opaque never-true guard keeps ldspad allocated (ws[WS_N] is 0 or ~3e4 here)
  if (__float_as_uint(ws[WS_N]) == 0xdeadbeefu) {
    ldspad[t & 1023] = xg[t];
    out[OUT_PERP] = ldspad[(t + 1) & 1023];
  }

  // ---- prologue: convert X tile (NEGATED) into fragment layout, 1 granule/thread ----
  {
    const int u  = t;                       // < 1024 granules
    const int rp = u >> 7, n = (u >> 3) & 15, g = u & 7;
    const float* src = xg + (size_t)(row0 + rp*16 + n)*64 + g*8;
    float4 v0 = *(const float4*)src, v1 = *(const float4*)(src + 4);
    float vv[8] = {v0.x,v0.y,v0.z,v0.w,v1.x,v1.y,v1.z,v1.w};
    f16x8 hi, lo;
#pragma unroll
    for (int j = 0; j < 8; ++j) { _Float16 h, l; split_f16(-vv[j], h, l); hi[j]=h; lo[j]=l; }
    const int slot = (g&3)*16 + n, shi = g >> 2;
    *(f16x8*)&xp[(((rp*4) + shi)*64 + slot)*8]     = hi;
    *(f16x8*)&xp[(((rp*4) + 2 + shi)*64 + slot)*8] = lo;
  }
  __syncthreads();

  // resident X frags (B operand): this wave's 64-row half, 4 tiles of 16 rows
  f16x8 b[4][4];
#pragma unroll
  for (int bt = 0; bt < 4; ++bt)
#pragma unroll
    for (int s = 0; s < 4; ++s)
      b[bt][s] = *(const f16x8*)&xp[(((rg*4+bt)*4 + s)*64 + lane)*8];

  float bestd[4]; int bestk[4];
#pragma unroll
  for (int i = 0; i < 4; ++i) { bestd[i] = INFINITY; bestk[i] = 0; }

  // W panel stream (panels cg, cg+8, ..., cg+8*63)
  const _Float16* wp = wfrag + (size_t)cg * 2048 + (size_t)lane * 8;
  const float*    cp = w2hg + cg*16 + quad*4;

  f16x8 wh0 = *(const f16x8*)(wp);
  f16x8 wh1 = *(const f16x8*)(wp + 512);
  f16x8 wl0 = *(const f16x8*)(wp + 1024);
  f16x8 wl1 = *(const f16x8*)(wp + 1536);
  f32x4 cw  = *(const f32x4*)(cp);
  wp += 16384; cp += 128;

  f32x4 accA[4], accB[4];
  int c0A = cg*16 + quad*4, c0B;

  MFMA_CLUSTER(accA);                       // panel 0 of this wave
  LOADNEXT();                               // panel 1 data

#pragma unroll 1
  for (int j = 0; j < 31; ++j) {            // panels 1..62 (pairs)
    MFMA_CLUSTER(accB);
    c0B = c0A + 128;
    LOADNEXT();
    TOURN(accA, c0A);
    MFMA_CLUSTER(accA);
    c0A = c0B + 128;
    LOADNEXT();
    TOURN(accB, c0B);
  }
  MFMA_CLUSTER(accB);                       // panel 63 (data already loaded)
  c0B = c0A + 128;
  TOURN(accA, c0A);
  TOURN(accB, c0B);

  // ---- merge across the 4 quads (same row, disjoint code slices) ----
#pragma unroll
  for (int bt = 0; bt < 4; ++bt) {
    float bd = bestd[bt]; int bk = bestk[bt];
#pragma unroll
    for (int m = 16; m < 64; m <<= 1) {
      const float od = __shfl_xor(bd, m, 64);
      const int   ok = __shfl_xor(bk, m, 64);
      if (od < bd || (od == bd && ok < bk)) { bd = od; bk = ok; }
    }
    if (lane < 16) {
      const int row = rg*64 + bt*16 + n16;
      md[row*8 + cg] = bd;
      mk[row*8 + cg] = bk;
    }
  }
  __syncthreads();

  if (t < 128) {
    const int row = t;
    float bd = md[row*8]; int bk = mk[row*8];
#pragma unroll
    for (int u2 = 1; u2 < 8; ++u2) {
      const float d2 = md[row*8 + u2]; const int k2 = mk[row*8 + u2];
      if (d2 < bd || (d2 == bd && k2 < bk)) { bd = d2; bk = k2; }
    }
    out[OUT_IDX + row0 + row] = (float)bk;
    ((int*)ws)[WS_IDX + row0 + row] = bk;
    bkL[row] = bk;
    atomicAdd(&ws[WS_COUNTS + bk], 1.0f);
  }
  __syncthreads();

  // ---- fused EMA segment-sum: 16 waves x 8 rows, lane = dim ----
#pragma unroll
  for (int r = 0; r < 8; ++r) {
    const int row = wv*8 + r;
    const int k = bkL[row];
    atomicAdd(&ws[WS_EMB + (size_t)k*64 + lane],
              xg[(size_t)(row0 + row)*64 + lane]);
  }

  // ---- last block runs the stats pass (replaces stats_kernel dispatch) ----
  __threadfence();
  if (t == 0) amLast = (atomicAdd((int*)ws + WS_CTR, 1) == (int)gridDim.x - 1);
  __syncthreads();
  if (amLast) {
    __threadfence();
    float v1 = 0.0f, v2 = 0.0f;
#pragma unroll
    for (int i = 0; i < 8; ++i) {
      const int k = i*1024 + t;
      const float cnt = ws[WS_COUNTS + k];
      const float ncc = __fadd_rn(__fmul_rn(DECAYF, cc[k]), __fmul_rn(OMDF, cnt));
      out[OUT_NCC + k] = ncc;
      const float p = cnt * (1.0f/32768.0f);
      v1 += ncc;
      v2 += __fmul_rn(p, logf(__fadd_rn(p, 1e-10f)));
    }
#pragma unroll
    for (int off = 32; off > 0; off >>= 1) {
      v1 += __shfl_down(v1, off);
      v2 += __shfl_down(v2, off);
    }
    if (lane == 0) { s1[wv] = v1; s2[wv] = v2; }
    __syncthreads();
    if (t == 0) {
      float a1 = 0.0f, a2 = 0.0f;
#pragma unroll
      for (int i = 0; i < 16; ++i) { a1 += s1[i]; a2 += s2[i]; }
      ws[WS_N]   = a1;
      ws[WS_ENT] = a2;
    }
  }
}

// fused update + quant + final loss: linear codebook update, gather-quantize
// with on-the-fly recompute of new_weight rows (bit-identical arithmetic),
// last block sums the per-block loss partials (deterministic fixed order).
__global__ __launch_bounds__(256) void update_quant_kernel(const float* __restrict__ xg,
                                                           const float* __restrict__ ws0,
                                                           float* __restrict__ out,
                                                           float* __restrict__ ws) {
  __shared__ float sm[4];
  __shared__ int amL;
  const int t = threadIdx.x;
  const float n = ws[WS_N];
  const float den = __fadd_rn(n, 0.08192f);

  // ---- linear codebook update: one float4 per thread ----
  const int e4 = blockIdx.x * 256 + t;      // < 131072 float4s
  {
    const int k = e4 >> 4;
    const float ncc = out[OUT_NCC + k];
    const float smoothed = __fmul_rn(__fadd_rn(ncc, 1e-5f) / den, n);
    float4 w0 = *(const float4*)(ws0 + (size_t)e4*4);
    float4 em = *(const float4*)(ws + WS_EMB + (size_t)e4*4);
    float wv4[4] = {w0.x, w0.y, w0.z, w0.w};
    float ev4[4] = {em.x, em.y, em.z, em.w};
    float nwsv[4], nwv[4];
#pragma unroll
    for (int i = 0; i < 4; ++i) {
      nwsv[i] = __fadd_rn(__fmul_rn(DECAYF, wv4[i]), __fmul_rn(OMDF, ev4[i]));
      nwv[i]  = nwsv[i] / smoothed;         // exact division (reference: nws / smoothed)
    }
    float4 onws = {nwsv[0], nwsv[1], nwsv[2], nwsv[3]};
    float4 onw  = {nwv[0],  nwv[1],  nwv[2],  nwv[3]};
    *(float4*)(out + OUT_NWS + (size_t)e4*4) = onws;
    *(float4*)(out + OUT_NW  + (size_t)e4*4) = onw;
    if (e4 == 0) out[OUT_PERP] = expf(-ws[WS_ENT]);
  }

  // ---- quant + loss partials (per-block slot in WS_COUNTS, post-stats reuse) ----
  const int* idxb = (const int*)ws + WS_IDX;
  float v = 0.0f;
#pragma unroll
  for (int j = 0; j < 4; ++j) {
    const int qe4 = (j*512 + blockIdx.x)*256 + t;   // float4 index, coalesced
    const int row = qe4 >> 4, d = (qe4 & 15) * 4;
    const int k = idxb[row];
    const float ncc = out[OUT_NCC + k];
    const float smK = __fmul_rn(__fadd_rn(ncc, 1e-5f) / den, n);
    float4 wq = *(const float4*)(ws0 + (size_t)k*64 + d);
    float4 eq = *(const float4*)(ws + WS_EMB + (size_t)k*64 + d);
    float4 x  = *(const float4*)(xg + (size_t)qe4*4);
    float wv4[4] = {wq.x,wq.y,wq.z,wq.w};
    float ev4[4] = {eq.x,eq.y,eq.z,eq.w};
    float xv[4]  = {x.x,x.y,x.z,x.w};
    float4 o; float ov[4];
#pragma unroll
    for (int i = 0; i < 4; ++i) {
      const float nws = __fadd_rn(__fmul_rn(DECAYF, wv4[i]), __fmul_rn(OMDF, ev4[i]));
      const float q = nws / smK;            // == new_weight[k][d+i], identical rounding
      const float df = __fsub_rn(q, xv[i]);
      ov[i] = __fadd_rn(xv[i], df);
      v = fmaf(df, df, v);
    }
    o.x = ov[0]; o.y = ov[1]; o.z = ov[2]; o.w = ov[3];
    *(float4*)(out + OUT_Q + (size_t)qe4*4) = o;
  }
#pragma unroll
  for (int off = 32; off > 0; off >>= 1) v += __shfl_down(v, off);
  const int lane = t & 63, wid = t >> 6;
  if (lane == 0) sm[wid] = v;
  __syncthreads();
  if (t == 0) ws[WS_COUNTS + blockIdx.x] = (sm[0]+sm[1]) + (sm[2]+sm[3]);

  // ---- last block computes final loss (replaces final_kernel dispatch) ----
  __threadfence();
  if (t == 0) amL = (atomicAdd((int*)ws + WS_CTR2, 1) == (int)gridDim.x - 1);
  __syncthreads();
  if (amL) {
    __threadfence();
    if (t < 64) {
      float vv = 0.0f;
#pragma unroll
      for (int i = 0; i < 8; ++i) vv += ws[WS_COUNTS + i*64 + t];
#pragma unroll
      for (int off = 32; off > 0; off >>= 1) vv += __shfl_down(vv, off);
      if (t == 0) out[OUT_LOSS] = __fmul_rn(0.25f, vv / 2097152.0f);
    }
  }
}

extern "C" void kernel_launch(void* const* d_in, const int* in_sizes, int n_in,
                              void* d_out, int out_size, void* d_ws, size_t ws_size,
                              hipStream_t stream) {
  (void)in_sizes; (void)n_in; (void)out_size; (void)ws_size;
  const float* x   = (const float*)d_in[0];
  const float* w   = (const float*)d_in[1];
  const float* cc  = (const float*)d_in[2];
  const float* ws0 = (const float*)d_in[3];
  float* out = (float*)d_out;
  float* ws  = (float*)d_ws;

  hipLaunchKernelGGL(prep_kernel,         dim3(288), dim3(256),  0, stream, w, ws);
  hipLaunchKernelGGL(argmin_kernel,       dim3(256), dim3(1024), 0, stream, x, cc, out, ws);
  hipLaunchKernelGGL(update_quant_kernel, dim3(512), dim3(256),  0, stream, x, ws0, out, ws);
}

// Round 4
// 188.109 us; speedup vs baseline: 1.5957x; 1.5957x over previous
//
#include <hip/hip_runtime.h>
#include <math.h>

typedef _Float16 f16x8 __attribute__((ext_vector_type(8)));
typedef float f32x4 __attribute__((ext_vector_type(4)));

// Problem constants
#define NROWS 32768   // 8*4096 input rows
#define KEMB  8192    // codebook entries
// DIM = 64

#define DECAYF 0.99f
#define OMDF   0.01f

// d_out layout (floats), reference return order
#define OUT_Q    0          // quantized, 2097152
#define OUT_LOSS 2097152    // vq_loss, 1
#define OUT_IDX  2097153    // idx (as float), 32768
#define OUT_PERP 2129921    // perplexity, 1
#define OUT_NW   2129922    // new_weight, 524288
#define OUT_NCC  2654210    // new_cc, 8192
#define OUT_NWS  2662402    // new_ws, 524288

// d_ws layout (4-byte units)
#define WS_N      0
#define WS_ENT    1
#define WS_COUNTS 4                    // 8192 floats (argmin atomics; reused as loss partials)
#define WS_EMB    8196                 // 524288 floats (atomic)
#define WS_IDX    532484               // 32768 ints
#define WS_W2H    565252               // 8192 floats (= ||w||^2 / 2)
#define WS_WFRAG  573444               // 524288 f32 units = 2 MB f16 frag image
#define WS_ZERO_UNITS 532484           // scalars+counts+emb

__device__ __forceinline__ float sq_rn(float v) { return __fmul_rn(v, v); }

// numpy pairwise_sum order for 64 contiguous squared values
__device__ __forceinline__ float npsumsq64(const float* vbuf) {
  float a[8];
#pragma unroll
  for (int j = 0; j < 8; ++j) a[j] = sq_rn(vbuf[j]);
#pragma unroll
  for (int m = 1; m < 8; ++m)
#pragma unroll
    for (int j = 0; j < 8; ++j) a[j] = __fadd_rn(a[j], sq_rn(vbuf[m*8 + j]));
  return __fadd_rn(__fadd_rn(__fadd_rn(a[0],a[1]), __fadd_rn(a[2],a[3])),
                   __fadd_rn(__fadd_rn(a[4],a[5]), __fadd_rn(a[6],a[7])));
}

// split a float into (hi, lo) fp16 pair; hi+lo reproduces x to ~22 bits
__device__ __forceinline__ void split_f16(float x, _Float16& hi, _Float16& lo) {
  hi = (_Float16)x;
  float r = __fsub_rn(x, (float)hi);   // exact (Sterbenz)
  lo = (_Float16)r;
}

// prep: w2h[k] = 0.5*||w_k||^2 (numpy order), W -> fragment-image f16 hi/lo.
// Image layout: frag(panel P, s, lane l) at wf[((P*4+s)*64+l)*8 .. +8];
// s=0,1 hi (K 0..31 / 32..63), s=2,3 lo. A per-lane dwordx4 load IS an MFMA frag.
__global__ __launch_bounds__(256) void prep_kernel(const float* __restrict__ wg,
                                                   float* __restrict__ ws) {
  const int tid = blockIdx.x * 256 + threadIdx.x;
  if (tid < KEMB) {
    const float* src = wg + (size_t)tid * 64;
    float vbuf[64];
#pragma unroll
    for (int f = 0; f < 16; ++f) {
      float4 v = *(const float4*)(src + f*4);
      vbuf[f*4+0]=v.x; vbuf[f*4+1]=v.y; vbuf[f*4+2]=v.z; vbuf[f*4+3]=v.w;
    }
    ws[WS_W2H + tid] = __fmul_rn(0.5f, npsumsq64(vbuf));
  } else if (tid < KEMB + 65536) {
    const int u = tid - KEMB;            // granule: code K, dims g*8..g*8+7
    const int K = u >> 3, g = u & 7;
    const int n = K & 15, P = K >> 4;    // global panel 0..511
    const int slot = (g&3)*16 + n, shi = g >> 2;
    const float* src = wg + (size_t)K*64 + g*8;
    float4 v0 = *(const float4*)src, v1 = *(const float4*)(src + 4);
    float vv[8] = {v0.x,v0.y,v0.z,v0.w,v1.x,v1.y,v1.z,v1.w};
    f16x8 hi, lo;
#pragma unroll
    for (int j = 0; j < 8; ++j) { _Float16 h, l; split_f16(vv[j], h, l); hi[j]=h; lo[j]=l; }
    _Float16* wf = (_Float16*)(ws + WS_WFRAG);
    *(f16x8*)&wf[((size_t)(P*4 + shi)*64 + slot)*8]     = hi;
    *(f16x8*)&wf[((size_t)(P*4 + 2 + shi)*64 + slot)*8] = lo;
  }
}

// one 16-code-panel MFMA cluster into ACC (C-in = cw = 0.5||w||^2, A = W frags,
// B = resident negated X frags) — distances bit-identical to prior versions.
#define MFMA_CLUSTER(ACC)                                                                     \
  __builtin_amdgcn_s_setprio(1);                                                              \
  _Pragma("unroll")                                                                           \
  for (int bt = 0; bt < 4; ++bt) ACC[bt] = __builtin_amdgcn_mfma_f32_16x16x32_f16(wh0, b[bt][0], cw,      0,0,0); \
  _Pragma("unroll")                                                                           \
  for (int bt = 0; bt < 4; ++bt) ACC[bt] = __builtin_amdgcn_mfma_f32_16x16x32_f16(wh1, b[bt][1], ACC[bt], 0,0,0); \
  _Pragma("unroll")                                                                           \
  for (int bt = 0; bt < 4; ++bt) ACC[bt] = __builtin_amdgcn_mfma_f32_16x16x32_f16(wh0, b[bt][2], ACC[bt], 0,0,0); \
  _Pragma("unroll")                                                                           \
  for (int bt = 0; bt < 4; ++bt) ACC[bt] = __builtin_amdgcn_mfma_f32_16x16x32_f16(wh1, b[bt][3], ACC[bt], 0,0,0); \
  _Pragma("unroll")                                                                           \
  for (int bt = 0; bt < 4; ++bt) ACC[bt] = __builtin_amdgcn_mfma_f32_16x16x32_f16(wl0, b[bt][0], ACC[bt], 0,0,0); \
  _Pragma("unroll")                                                                           \
  for (int bt = 0; bt < 4; ++bt) ACC[bt] = __builtin_amdgcn_mfma_f32_16x16x32_f16(wl1, b[bt][1], ACC[bt], 0,0,0); \
  __builtin_amdgcn_s_setprio(0);

#define LOADNEXT()                                  \
  wh0 = *(const f16x8*)(wp);                        \
  wh1 = *(const f16x8*)(wp + 512);                  \
  wl0 = *(const f16x8*)(wp + 1024);                 \
  wl1 = *(const f16x8*)(wp + 1536);                 \
  cw  = *(const f32x4*)(cp);                        \
  wp += 8192; cp += 64;

// deferred tournament: runs on the PREVIOUS panel's acc (no RAW on the MFMA
// cluster just issued) -> VALU overlaps matrix-pipe work across waves.
#define TOURN(ACC, C0)                                                       \
  _Pragma("unroll")                                                          \
  for (int bt = 0; bt < 4; ++bt) {                                           \
    const float d0 = ACC[bt][0], d1 = ACC[bt][1], d2 = ACC[bt][2], d3 = ACC[bt][3]; \
    const float pm = fminf(fminf(d0, d1), fminf(d2, d3));                    \
    int koff = 3;                                                            \
    if (d2 == pm) koff = 2;                                                  \
    if (d1 == pm) koff = 1;                                                  \
    if (d0 == pm) koff = 0;                                                  \
    if (pm < bestd[bt]) { bestd[bt] = pm; bestk[bt] = (C0) + koff; }         \
  }

// argmin v10: 512 blocks x 256 threads (4 waves = cg0..3), 64 rows/block.
// 4-wave blocks lift the per-wave register ceiling to 256 (launch_bounds(256,2)),
// so the deferred accA/accB tournament (~145 regs/wave) fits WITHOUT spilling
// (r3's 16-wave blocks had a hard 128/wave cap -> scratch spill, +19MB traffic).
// Each wave: all 64 resident X rows (b[4][4]), code slice cg: 128 panels of 16.
// Deferral removes the tournament->own-cluster RAW that phase-locked r2
// (MfmaUtil 49 + VALUBusy 46 = serialized sum).
__global__ __launch_bounds__(256, 2) void argmin_kernel(const float* __restrict__ xg,
                                                        float* __restrict__ out,
                                                        float* __restrict__ ws) {
  __shared__ __align__(16) _Float16 xp[4*4*64*8];   // 16 KB, X frags (negated)
  __shared__ float md[64*4];
  __shared__ int   mk[64*4];
  __shared__ int   bkL[64];

  const int t    = threadIdx.x;
  const int lane = t & 63, wv = t >> 6;     // wv 0..3
  const int quad = lane >> 4, n16 = lane & 15;
  const int cg = wv;                        // code slice 0..3
  const int row0 = blockIdx.x * 64;
  const _Float16* __restrict__ wfrag = (const _Float16*)(ws + WS_WFRAG);
  const float* __restrict__ w2hg = ws + WS_W2H;

  // ---- prologue: convert X tile (NEGATED) into fragment layout ----
#pragma unroll
  for (int it = 0; it < 2; ++it) {
    const int u  = t + 256*it;              // < 512 granules (64 rows)
    const int rp = u >> 7, n = (u >> 3) & 15, g = u & 7;
    const float* src = xg + (size_t)(row0 + rp*16 + n)*64 + g*8;
    float4 v0 = *(const float4*)src, v1 = *(const float4*)(src + 4);
    float vv[8] = {v0.x,v0.y,v0.z,v0.w,v1.x,v1.y,v1.z,v1.w};
    f16x8 hi, lo;
#pragma unroll
    for (int j = 0; j < 8; ++j) { _Float16 h, l; split_f16(-vv[j], h, l); hi[j]=h; lo[j]=l; }
    const int slot = (g&3)*16 + n, shi = g >> 2;
    *(f16x8*)&xp[(((rp*4) + shi)*64 + slot)*8]     = hi;
    *(f16x8*)&xp[(((rp*4) + 2 + shi)*64 + slot)*8] = lo;
  }
  __syncthreads();

  // resident X frags (B operand): all 64 rows of this block, 4 tiles of 16
  f16x8 b[4][4];
#pragma unroll
  for (int bt = 0; bt < 4; ++bt)
#pragma unroll
    for (int s = 0; s < 4; ++s)
      b[bt][s] = *(const f16x8*)&xp[(((bt*4) + s)*64 + lane)*8];

  float bestd[4]; int bestk[4];
#pragma unroll
  for (int i = 0; i < 4; ++i) { bestd[i] = INFINITY; bestk[i] = 0; }

  const int q4 = quad * 4;

  // W panel stream: panels cg, cg+4, ..., cg+4*127 (128 panels)
  const _Float16* wp = wfrag + (size_t)cg * 2048 + (size_t)lane * 8;
  const float*    cp = w2hg + cg*16 + q4;

  f16x8 wh0, wh1, wl0, wl1;
  f32x4 cw;
  LOADNEXT();                               // panel m=0 data

  f32x4 accA[4], accB[4];
  int c0A = cg*16 + q4, c0B;

  MFMA_CLUSTER(accA);                       // panel 0
  LOADNEXT();                               // panel 1 data

#pragma unroll 1
  for (int j = 0; j < 63; ++j) {            // panels 1..126 (pairs)
    MFMA_CLUSTER(accB);                     // panel 2j+1
    c0B = c0A + 64;
    LOADNEXT();                             // panel 2j+2
    TOURN(accA, c0A);                       // panel 2j (deferred, no RAW)
    MFMA_CLUSTER(accA);                     // panel 2j+2
    c0A = c0B + 64;
    LOADNEXT();                             // panel 2j+3
    TOURN(accB, c0B);                       // panel 2j+1
  }
  MFMA_CLUSTER(accB);                       // panel 127 (data already loaded)
  c0B = c0A + 64;
  TOURN(accA, c0A);
  TOURN(accB, c0B);

  // ---- merge across the 4 quads (same row, disjoint code slices) ----
#pragma unroll
  for (int bt = 0; bt < 4; ++bt) {
    float bd = bestd[bt]; int bk = bestk[bt];
#pragma unroll
    for (int m = 16; m < 64; m <<= 1) {
      const float od = __shfl_xor(bd, m, 64);
      const int   ok = __shfl_xor(bk, m, 64);
      if (od < bd || (od == bd && ok < bk)) { bd = od; bk = ok; }
    }
    if (lane < 16) {
      const int row = bt*16 + n16;
      md[row*4 + cg] = bd;
      mk[row*4 + cg] = bk;
    }
  }
  __syncthreads();

  if (t < 64) {
    const int row = t;
    float bd = md[row*4]; int bk = mk[row*4];
#pragma unroll
    for (int u2 = 1; u2 < 4; ++u2) {
      const float d2 = md[row*4 + u2]; const int k2 = mk[row*4 + u2];
      if (d2 < bd || (d2 == bd && k2 < bk)) { bd = d2; bk = k2; }
    }
    out[OUT_IDX + row0 + row] = (float)bk;
    ((int*)ws)[WS_IDX + row0 + row] = bk;
    bkL[row] = bk;
    atomicAdd(&ws[WS_COUNTS + bk], 1.0f);
  }
  __syncthreads();

  // ---- fused EMA segment-sum: 4 waves x 16 rows, lane = dim ----
#pragma unroll 4
  for (int r = 0; r < 16; ++r) {
    const int row = wv*16 + r;
    const int k = bkL[row];
    atomicAdd(&ws[WS_EMB + (size_t)k*64 + lane],
              xg[(size_t)(row0 + row)*64 + lane]);
  }
}

// stats: ONE block, no atomics
__global__ __launch_bounds__(256) void stats_kernel(const float* __restrict__ cc,
                                                    float* __restrict__ out,
                                                    float* __restrict__ ws) {
  const int t = threadIdx.x;
  float v1 = 0.0f, v2 = 0.0f;
#pragma unroll
  for (int i = 0; i < 32; ++i) {
    const int k = i*256 + t;
    const float cnt = ws[WS_COUNTS + k];
    const float ncc = __fadd_rn(__fmul_rn(DECAYF, cc[k]), __fmul_rn(OMDF, cnt));
    out[OUT_NCC + k] = ncc;
    const float p = cnt * (1.0f/32768.0f);
    v1 += ncc;
    v2 += __fmul_rn(p, logf(__fadd_rn(p, 1e-10f)));
  }
#pragma unroll
  for (int off = 32; off > 0; off >>= 1) {
    v1 += __shfl_down(v1, off);
    v2 += __shfl_down(v2, off);
  }
  __shared__ float s1[4], s2[4];
  const int lane = t & 63, wid = t >> 6;
  if (lane == 0) { s1[wid] = v1; s2[wid] = v2; }
  __syncthreads();
  if (t == 0) {
    ws[WS_N]   = (s1[0]+s1[1]) + (s1[2]+s1[3]);
    ws[WS_ENT] = (s2[0]+s2[1]) + (s2[2]+s2[3]);
  }
}

// fused update + quant: linear codebook update, then gather-quantize with
// on-the-fly recompute of new_weight rows (bit-identical arithmetic).
__global__ __launch_bounds__(256) void update_quant_kernel(const float* __restrict__ xg,
                                                           const float* __restrict__ ws0,
                                                           float* __restrict__ out,
                                                           float* __restrict__ ws) {
  const int t = threadIdx.x;
  const float n = ws[WS_N];
  const float den = __fadd_rn(n, 0.08192f);

  // ---- linear codebook update: one float4 per thread ----
  const int e4 = blockIdx.x * 256 + t;      // < 131072 float4s
  {
    const int k = e4 >> 4;
    const float ncc = out[OUT_NCC + k];
    const float smoothed = __fmul_rn(__fadd_rn(ncc, 1e-5f) / den, n);
    float4 w0 = *(const float4*)(ws0 + (size_t)e4*4);
    float4 em = *(const float4*)(ws + WS_EMB + (size_t)e4*4);
    float wv4[4] = {w0.x, w0.y, w0.z, w0.w};
    float ev4[4] = {em.x, em.y, em.z, em.w};
    float nwsv[4], nwv[4];
#pragma unroll
    for (int i = 0; i < 4; ++i) {
      nwsv[i] = __fadd_rn(__fmul_rn(DECAYF, wv4[i]), __fmul_rn(OMDF, ev4[i]));
      nwv[i]  = nwsv[i] / smoothed;         // exact division (reference: nws / smoothed)
    }
    float4 onws = {nwsv[0], nwsv[1], nwsv[2], nwsv[3]};
    float4 onw  = {nwv[0],  nwv[1],  nwv[2],  nwv[3]};
    *(float4*)(out + OUT_NWS + (size_t)e4*4) = onws;
    *(float4*)(out + OUT_NW  + (size_t)e4*4) = onw;
    if (e4 == 0) out[OUT_PERP] = expf(-ws[WS_ENT]);
  }

  // ---- quant + loss partials (per-block slot in WS_COUNTS, post-stats reuse) ----
  const int* idxb = (const int*)ws + WS_IDX;
  float v = 0.0f;
#pragma unroll
  for (int j = 0; j < 4; ++j) {
    const int qe4 = (j*512 + blockIdx.x)*256 + t;   // float4 index, coalesced
    const int row = qe4 >> 4, d = (qe4 & 15) * 4;
    const int k = idxb[row];
    const float ncc = out[OUT_NCC + k];
    const float smK = __fmul_rn(__fadd_rn(ncc, 1e-5f) / den, n);
    float4 wq = *(const float4*)(ws0 + (size_t)k*64 + d);
    float4 eq = *(const float4*)(ws + WS_EMB + (size_t)k*64 + d);
    float4 x  = *(const float4*)(xg + (size_t)qe4*4);
    float wv4[4] = {wq.x,wq.y,wq.z,wq.w};
    float ev4[4] = {eq.x,eq.y,eq.z,eq.w};
    float xv[4]  = {x.x,x.y,x.z,x.w};
    float4 o; float ov[4];
#pragma unroll
    for (int i = 0; i < 4; ++i) {
      const float nws = __fadd_rn(__fmul_rn(DECAYF, wv4[i]), __fmul_rn(OMDF, ev4[i]));
      const float q = nws / smK;            // == new_weight[k][d+i], identical rounding
      const float df = __fsub_rn(q, xv[i]);
      ov[i] = __fadd_rn(xv[i], df);
      v = fmaf(df, df, v);
    }
    o.x = ov[0]; o.y = ov[1]; o.z = ov[2]; o.w = ov[3];
    *(float4*)(out + OUT_Q + (size_t)qe4*4) = o;
  }
#pragma unroll
  for (int off = 32; off > 0; off >>= 1) v += __shfl_down(v, off);
  __shared__ float sm[4];
  const int lane = t & 63, wid = t >> 6;
  if (lane == 0) sm[wid] = v;
  __syncthreads();
  if (t == 0) ws[WS_COUNTS + blockIdx.x] = (sm[0]+sm[1]) + (sm[2]+sm[3]);
}

__global__ void final_kernel(float* __restrict__ out, const float* __restrict__ ws) {
  const int t = threadIdx.x;   // 64 threads
  float v = 0.0f;
#pragma unroll
  for (int i = 0; i < 8; ++i) v += ws[WS_COUNTS + i*64 + t];
#pragma unroll
  for (int off = 32; off > 0; off >>= 1) v += __shfl_down(v, off);
  if (t == 0) out[OUT_LOSS] = __fmul_rn(0.25f, v / 2097152.0f);
}

extern "C" void kernel_launch(void* const* d_in, const int* in_sizes, int n_in,
                              void* d_out, int out_size, void* d_ws, size_t ws_size,
                              hipStream_t stream) {
  (void)in_sizes; (void)n_in; (void)out_size; (void)ws_size;
  const float* x   = (const float*)d_in[0];
  const float* w   = (const float*)d_in[1];
  const float* cc  = (const float*)d_in[2];
  const float* ws0 = (const float*)d_in[3];
  float* out = (float*)d_out;
  float* ws  = (float*)d_ws;

  hipMemsetAsync(d_ws, 0, (size_t)WS_ZERO_UNITS * 4, stream);
  hipLaunchKernelGGL(prep_kernel,         dim3(288), dim3(256), 0, stream, w, ws);
  hipLaunchKernelGGL(argmin_kernel,       dim3(512), dim3(256), 0, stream, x, out, ws);
  hipLaunchKernelGGL(stats_kernel,        dim3(1),   dim3(256), 0, stream, cc, out, ws);
  hipLaunchKernelGGL(update_quant_kernel, dim3(512), dim3(256), 0, stream, x, ws0, out, ws);
  hipLaunchKernelGGL(final_kernel,        dim3(1),   dim3(64),  0, stream, out, ws);
}

// Round 5
// 179.041 us; speedup vs baseline: 1.6765x; 1.0507x over previous
//
#include <hip/hip_runtime.h>
#include <math.h>

typedef _Float16 f16x8 __attribute__((ext_vector_type(8)));
typedef float f32x4 __attribute__((ext_vector_type(4)));

// Problem constants
#define NROWS 32768   // 8*4096 input rows
#define KEMB  8192    // codebook entries
// DIM = 64

#define DECAYF 0.99f
#define OMDF   0.01f

// d_out layout (floats), reference return order
#define OUT_Q    0          // quantized, 2097152
#define OUT_LOSS 2097152    // vq_loss, 1
#define OUT_IDX  2097153    // idx (as float), 32768
#define OUT_PERP 2129921    // perplexity, 1
#define OUT_NW   2129922    // new_weight, 524288
#define OUT_NCC  2654210    // new_cc, 8192
#define OUT_NWS  2662402    // new_ws, 524288

// d_ws layout (4-byte units)
#define WS_N      0
#define WS_ENT    1
#define WS_COUNTS 4                    // 8192 floats (argmin atomics; reused as loss partials)
#define WS_EMB    8196                 // 524288 floats (atomic)
#define WS_IDX    532484               // 32768 ints
#define WS_W2H    565252               // 8192 floats (= ||w||^2 / 2)
#define WS_WFRAG  573444               // 524288 f32 units = 2 MB f16 frag image
#define WS_ZERO_UNITS 532484           // scalars+counts+emb

__device__ __forceinline__ float sq_rn(float v) { return __fmul_rn(v, v); }

// numpy pairwise_sum order for 64 contiguous squared values
__device__ __forceinline__ float npsumsq64(const float* vbuf) {
  float a[8];
#pragma unroll
  for (int j = 0; j < 8; ++j) a[j] = sq_rn(vbuf[j]);
#pragma unroll
  for (int m = 1; m < 8; ++m)
#pragma unroll
    for (int j = 0; j < 8; ++j) a[j] = __fadd_rn(a[j], sq_rn(vbuf[m*8 + j]));
  return __fadd_rn(__fadd_rn(__fadd_rn(a[0],a[1]), __fadd_rn(a[2],a[3])),
                   __fadd_rn(__fadd_rn(a[4],a[5]), __fadd_rn(a[6],a[7])));
}

// split a float into (hi, lo) fp16 pair; hi+lo reproduces x to ~22 bits
__device__ __forceinline__ void split_f16(float x, _Float16& hi, _Float16& lo) {
  hi = (_Float16)x;
  float r = __fsub_rn(x, (float)hi);   // exact (Sterbenz)
  lo = (_Float16)r;
}

// prep: w2h[k] = 0.5*||w_k||^2 (numpy order), W -> fragment-image f16 hi/lo.
// Image layout: frag(panel P, s, lane l) at wf[((P*4+s)*64+l)*8 .. +8];
// s=0,1 hi (K 0..31 / 32..63), s=2,3 lo. A per-lane dwordx4 load IS an MFMA frag.
__global__ __launch_bounds__(256) void prep_kernel(const float* __restrict__ wg,
                                                   float* __restrict__ ws) {
  const int tid = blockIdx.x * 256 + threadIdx.x;
  if (tid < KEMB) {
    const float* src = wg + (size_t)tid * 64;
    float vbuf[64];
#pragma unroll
    for (int f = 0; f < 16; ++f) {
      float4 v = *(const float4*)(src + f*4);
      vbuf[f*4+0]=v.x; vbuf[f*4+1]=v.y; vbuf[f*4+2]=v.z; vbuf[f*4+3]=v.w;
    }
    ws[WS_W2H + tid] = __fmul_rn(0.5f, npsumsq64(vbuf));
  } else if (tid < KEMB + 65536) {
    const int u = tid - KEMB;            // granule: code K, dims g*8..g*8+7
    const int K = u >> 3, g = u & 7;
    const int n = K & 15, P = K >> 4;    // global panel 0..511
    const int slot = (g&3)*16 + n, shi = g >> 2;
    const float* src = wg + (size_t)K*64 + g*8;
    float4 v0 = *(const float4*)src, v1 = *(const float4*)(src + 4);
    float vv[8] = {v0.x,v0.y,v0.z,v0.w,v1.x,v1.y,v1.z,v1.w};
    f16x8 hi, lo;
#pragma unroll
    for (int j = 0; j < 8; ++j) { _Float16 h, l; split_f16(vv[j], h, l); hi[j]=h; lo[j]=l; }
    _Float16* wf = (_Float16*)(ws + WS_WFRAG);
    *(f16x8*)&wf[((size_t)(P*4 + shi)*64 + slot)*8]     = hi;
    *(f16x8*)&wf[((size_t)(P*4 + 2 + shi)*64 + slot)*8] = lo;
  }
}

// one 16-code-panel MFMA cluster into ACC (C-in = CW = 0.5||w||^2, A = W frags,
// B = resident negated X frags) — distances bit-identical to prior versions.
#define MFMA_CLUSTER(ACC, H0, H1, L0, L1, CW)                                                 \
  __builtin_amdgcn_s_setprio(1);                                                              \
  _Pragma("unroll")                                                                           \
  for (int bt = 0; bt < 4; ++bt) ACC[bt] = __builtin_amdgcn_mfma_f32_16x16x32_f16(H0, b[bt][0], CW,      0,0,0); \
  _Pragma("unroll")                                                                           \
  for (int bt = 0; bt < 4; ++bt) ACC[bt] = __builtin_amdgcn_mfma_f32_16x16x32_f16(H1, b[bt][1], ACC[bt], 0,0,0); \
  _Pragma("unroll")                                                                           \
  for (int bt = 0; bt < 4; ++bt) ACC[bt] = __builtin_amdgcn_mfma_f32_16x16x32_f16(H0, b[bt][2], ACC[bt], 0,0,0); \
  _Pragma("unroll")                                                                           \
  for (int bt = 0; bt < 4; ++bt) ACC[bt] = __builtin_amdgcn_mfma_f32_16x16x32_f16(H1, b[bt][3], ACC[bt], 0,0,0); \
  _Pragma("unroll")                                                                           \
  for (int bt = 0; bt < 4; ++bt) ACC[bt] = __builtin_amdgcn_mfma_f32_16x16x32_f16(L0, b[bt][0], ACC[bt], 0,0,0); \
  _Pragma("unroll")                                                                           \
  for (int bt = 0; bt < 4; ++bt) ACC[bt] = __builtin_amdgcn_mfma_f32_16x16x32_f16(L1, b[bt][1], ACC[bt], 0,0,0); \
  __builtin_amdgcn_s_setprio(0);

// stream load of one panel into a named register set; pointer advances by
// 2 panels' stride (each set handles every other panel of this wave's slice)
#define LOADP(H0, H1, L0, L1, CW, WP, CP)           \
  H0 = *(const f16x8*)(WP);                         \
  H1 = *(const f16x8*)(WP + 512);                   \
  L0 = *(const f16x8*)(WP + 1024);                  \
  L1 = *(const f16x8*)(WP + 1536);                  \
  CW = *(const f32x4*)(CP);                         \
  WP += 16384; CP += 128;

// deferred tournament: runs on an acc whose cluster completed a full phase ago
#define TOURN(ACC, C0)                                                       \
  _Pragma("unroll")                                                          \
  for (int bt = 0; bt < 4; ++bt) {                                           \
    const float d0 = ACC[bt][0], d1 = ACC[bt][1], d2 = ACC[bt][2], d3 = ACC[bt][3]; \
    const float pm = fminf(fminf(d0, d1), fminf(d2, d3));                    \
    int koff = 3;                                                            \
    if (d2 == pm) koff = 2;                                                  \
    if (d1 == pm) koff = 1;                                                  \
    if (d0 == pm) koff = 0;                                                  \
    if (pm < bestd[bt]) { bestd[bt] = pm; bestk[bt] = (C0) + koff; }         \
  }

// argmin v11: 512 blocks x 256 threads (4 waves = cg0..3), 64 rows/block.
// 2-panel-deep W-stream prefetch: register setA feeds even panels, setB odd.
// Loads for a panel are issued a full opposite-phase earlier (~660cy before
// use vs ~100-200cy in v10), so L2 latency (~250cy) is fully covered and the
// per-cluster vmcnt stall (~410cy/panel idle in r4 counters) disappears.
// Steady state: exactly 5 loads in flight (counted vmcnt, never drained).
// Panel order and tournament order unchanged -> bit-identical outputs.
__global__ __launch_bounds__(256, 2) void argmin_kernel(const float* __restrict__ xg,
                                                        float* __restrict__ out,
                                                        float* __restrict__ ws) {
  __shared__ __align__(16) _Float16 xp[4*4*64*8];   // 16 KB, X frags (negated)
  __shared__ float md[64*4];
  __shared__ int   mk[64*4];
  __shared__ int   bkL[64];

  const int t    = threadIdx.x;
  const int lane = t & 63, wv = t >> 6;     // wv 0..3
  const int quad = lane >> 4, n16 = lane & 15;
  const int cg = wv;                        // code slice 0..3
  const int row0 = blockIdx.x * 64;
  const _Float16* __restrict__ wfrag = (const _Float16*)(ws + WS_WFRAG);
  const float* __restrict__ w2hg = ws + WS_W2H;

  // ---- prologue: convert X tile (NEGATED) into fragment layout ----
#pragma unroll
  for (int it = 0; it < 2; ++it) {
    const int u  = t + 256*it;              // < 512 granules (64 rows)
    const int rp = u >> 7, n = (u >> 3) & 15, g = u & 7;
    const float* src = xg + (size_t)(row0 + rp*16 + n)*64 + g*8;
    float4 v0 = *(const float4*)src, v1 = *(const float4*)(src + 4);
    float vv[8] = {v0.x,v0.y,v0.z,v0.w,v1.x,v1.y,v1.z,v1.w};
    f16x8 hi, lo;
#pragma unroll
    for (int j = 0; j < 8; ++j) { _Float16 h, l; split_f16(-vv[j], h, l); hi[j]=h; lo[j]=l; }
    const int slot = (g&3)*16 + n, shi = g >> 2;
    *(f16x8*)&xp[(((rp*4) + shi)*64 + slot)*8]     = hi;
    *(f16x8*)&xp[(((rp*4) + 2 + shi)*64 + slot)*8] = lo;
  }
  __syncthreads();

  // resident X frags (B operand): all 64 rows of this block, 4 tiles of 16
  f16x8 b[4][4];
#pragma unroll
  for (int bt = 0; bt < 4; ++bt)
#pragma unroll
    for (int s = 0; s < 4; ++s)
      b[bt][s] = *(const f16x8*)&xp[(((bt*4) + s)*64 + lane)*8];

  float bestd[4]; int bestk[4];
#pragma unroll
  for (int i = 0; i < 4; ++i) { bestd[i] = INFINITY; bestk[i] = 0; }

  const int q4 = quad * 4;

  // W panel stream: this wave covers panels cg, cg+4, ..., cg+4*127.
  // setA sweeps even-m panels (stride 2*8192 halves), setB odd-m panels.
  const _Float16* wpA = wfrag + (size_t)cg * 2048 + (size_t)lane * 8;
  const _Float16* wpB = wpA + 8192;
  const float*    cpA = w2hg + cg*16 + q4;
  const float*    cpB = cpA + 64;

  f16x8 hA0, hA1, lA0, lA1, hB0, hB1, lB0, lB1;
  f32x4 cwA, cwB;

  LOADP(hA0, hA1, lA0, lA1, cwA, wpA, cpA);   // panel 0
  LOADP(hB0, hB1, lB0, lB1, cwB, wpB, cpB);   // panel 1

  f32x4 accA[4], accB[4];
  int c0A = cg*16 + q4;                       // panel 0 codes
  int c0B = c0A + 64;                         // panel 1 codes

  MFMA_CLUSTER(accA, hA0, hA1, lA0, lA1, cwA);   // panel 0
  LOADP(hA0, hA1, lA0, lA1, cwA, wpA, cpA);      // panel 2 (2-deep)

#pragma unroll 1
  for (int j = 0; j < 63; ++j) {
    MFMA_CLUSTER(accB, hB0, hB1, lB0, lB1, cwB); // panel 2j+1 (loaded 1 phase ago)
    LOADP(hB0, hB1, lB0, lB1, cwB, wpB, cpB);    // panel 2j+3
    TOURN(accA, c0A);                            // panel 2j
    MFMA_CLUSTER(accA, hA0, hA1, lA0, lA1, cwA); // panel 2j+2
    c0A += 128;
    if (j < 62) { LOADP(hA0, hA1, lA0, lA1, cwA, wpA, cpA); }  // panel 2j+4
    TOURN(accB, c0B);                            // panel 2j+1
    c0B += 128;
  }
  MFMA_CLUSTER(accB, hB0, hB1, lB0, lB1, cwB);   // panel 127
  TOURN(accA, c0A);                              // panel 126
  TOURN(accB, c0B);                              // panel 127

  // ---- merge across the 4 quads (same row, disjoint code slices) ----
#pragma unroll
  for (int bt = 0; bt < 4; ++bt) {
    float bd = bestd[bt]; int bk = bestk[bt];
#pragma unroll
    for (int m = 16; m < 64; m <<= 1) {
      const float od = __shfl_xor(bd, m, 64);
      const int   ok = __shfl_xor(bk, m, 64);
      if (od < bd || (od == bd && ok < bk)) { bd = od; bk = ok; }
    }
    if (lane < 16) {
      const int row = bt*16 + n16;
      md[row*4 + cg] = bd;
      mk[row*4 + cg] = bk;
    }
  }
  __syncthreads();

  if (t < 64) {
    const int row = t;
    float bd = md[row*4]; int bk = mk[row*4];
#pragma unroll
    for (int u2 = 1; u2 < 4; ++u2) {
      const float d2 = md[row*4 + u2]; const int k2 = mk[row*4 + u2];
      if (d2 < bd || (d2 == bd && k2 < bk)) { bd = d2; bk = k2; }
    }
    out[OUT_IDX + row0 + row] = (float)bk;
    ((int*)ws)[WS_IDX + row0 + row] = bk;
    bkL[row] = bk;
    atomicAdd(&ws[WS_COUNTS + bk], 1.0f);
  }
  __syncthreads();

  // ---- fused EMA segment-sum: 4 waves x 16 rows, lane = dim ----
#pragma unroll 4
  for (int r = 0; r < 16; ++r) {
    const int row = wv*16 + r;
    const int k = bkL[row];
    atomicAdd(&ws[WS_EMB + (size_t)k*64 + lane],
              xg[(size_t)(row0 + row)*64 + lane]);
  }
}

// stats: ONE block, no atomics
__global__ __launch_bounds__(256) void stats_kernel(const float* __restrict__ cc,
                                                    float* __restrict__ out,
                                                    float* __restrict__ ws) {
  const int t = threadIdx.x;
  float v1 = 0.0f, v2 = 0.0f;
#pragma unroll
  for (int i = 0; i < 32; ++i) {
    const int k = i*256 + t;
    const float cnt = ws[WS_COUNTS + k];
    const float ncc = __fadd_rn(__fmul_rn(DECAYF, cc[k]), __fmul_rn(OMDF, cnt));
    out[OUT_NCC + k] = ncc;
    const float p = cnt * (1.0f/32768.0f);
    v1 += ncc;
    v2 += __fmul_rn(p, logf(__fadd_rn(p, 1e-10f)));
  }
#pragma unroll
  for (int off = 32; off > 0; off >>= 1) {
    v1 += __shfl_down(v1, off);
    v2 += __shfl_down(v2, off);
  }
  __shared__ float s1[4], s2[4];
  const int lane = t & 63, wid = t >> 6;
  if (lane == 0) { s1[wid] = v1; s2[wid] = v2; }
  __syncthreads();
  if (t == 0) {
    ws[WS_N]   = (s1[0]+s1[1]) + (s1[2]+s1[3]);
    ws[WS_ENT] = (s2[0]+s2[1]) + (s2[2]+s2[3]);
  }
}

// fused update + quant: linear codebook update, then gather-quantize with
// on-the-fly recompute of new_weight rows (bit-identical arithmetic).
__global__ __launch_bounds__(256) void update_quant_kernel(const float* __restrict__ xg,
                                                           const float* __restrict__ ws0,
                                                           float* __restrict__ out,
                                                           float* __restrict__ ws) {
  const int t = threadIdx.x;
  const float n = ws[WS_N];
  const float den = __fadd_rn(n, 0.08192f);

  // ---- linear codebook update: one float4 per thread ----
  const int e4 = blockIdx.x * 256 + t;      // < 131072 float4s
  {
    const int k = e4 >> 4;
    const float ncc = out[OUT_NCC + k];
    const float smoothed = __fmul_rn(__fadd_rn(ncc, 1e-5f) / den, n);
    float4 w0 = *(const float4*)(ws0 + (size_t)e4*4);
    float4 em = *(const float4*)(ws + WS_EMB + (size_t)e4*4);
    float wv4[4] = {w0.x, w0.y, w0.z, w0.w};
    float ev4[4] = {em.x, em.y, em.z, em.w};
    float nwsv[4], nwv[4];
#pragma unroll
    for (int i = 0; i < 4; ++i) {
      nwsv[i] = __fadd_rn(__fmul_rn(DECAYF, wv4[i]), __fmul_rn(OMDF, ev4[i]));
      nwv[i]  = nwsv[i] / smoothed;         // exact division (reference: nws / smoothed)
    }
    float4 onws = {nwsv[0], nwsv[1], nwsv[2], nwsv[3]};
    float4 onw  = {nwv[0],  nwv[1],  nwv[2],  nwv[3]};
    *(float4*)(out + OUT_NWS + (size_t)e4*4) = onws;
    *(float4*)(out + OUT_NW  + (size_t)e4*4) = onw;
    if (e4 == 0) out[OUT_PERP] = expf(-ws[WS_ENT]);
  }

  // ---- quant + loss partials (per-block slot in WS_COUNTS, post-stats reuse) ----
  const int* idxb = (const int*)ws + WS_IDX;
  float v = 0.0f;
#pragma unroll
  for (int j = 0; j < 4; ++j) {
    const int qe4 = (j*512 + blockIdx.x)*256 + t;   // float4 index, coalesced
    const int row = qe4 >> 4, d = (qe4 & 15) * 4;
    const int k = idxb[row];
    const float ncc = out[OUT_NCC + k];
    const float smK = __fmul_rn(__fadd_rn(ncc, 1e-5f) / den, n);
    float4 wq = *(const float4*)(ws0 + (size_t)k*64 + d);
    float4 eq = *(const float4*)(ws + WS_EMB + (size_t)k*64 + d);
    float4 x  = *(const float4*)(xg + (size_t)qe4*4);
    float wv4[4] = {wq.x,wq.y,wq.z,wq.w};
    float ev4[4] = {eq.x,eq.y,eq.z,eq.w};
    float xv[4]  = {x.x,x.y,x.z,x.w};
    float4 o; float ov[4];
#pragma unroll
    for (int i = 0; i < 4; ++i) {
      const float nws = __fadd_rn(__fmul_rn(DECAYF, wv4[i]), __fmul_rn(OMDF, ev4[i]));
      const float q = nws / smK;            // == new_weight[k][d+i], identical rounding
      const float df = __fsub_rn(q, xv[i]);
      ov[i] = __fadd_rn(xv[i], df);
      v = fmaf(df, df, v);
    }
    o.x = ov[0]; o.y = ov[1]; o.z = ov[2]; o.w = ov[3];
    *(float4*)(out + OUT_Q + (size_t)qe4*4) = o;
  }
#pragma unroll
  for (int off = 32; off > 0; off >>= 1) v += __shfl_down(v, off);
  __shared__ float sm[4];
  const int lane = t & 63, wid = t >> 6;
  if (lane == 0) sm[wid] = v;
  __syncthreads();
  if (t == 0) ws[WS_COUNTS + blockIdx.x] = (sm[0]+sm[1]) + (sm[2]+sm[3]);
}

__global__ void final_kernel(float* __restrict__ out, const float* __restrict__ ws) {
  const int t = threadIdx.x;   // 64 threads
  float v = 0.0f;
#pragma unroll
  for (int i = 0; i < 8; ++i) v += ws[WS_COUNTS + i*64 + t];
#pragma unroll
  for (int off = 32; off > 0; off >>= 1) v += __shfl_down(v, off);
  if (t == 0) out[OUT_LOSS] = __fmul_rn(0.25f, v / 2097152.0f);
}

extern "C" void kernel_launch(void* const* d_in, const int* in_sizes, int n_in,
                              void* d_out, int out_size, void* d_ws, size_t ws_size,
                              hipStream_t stream) {
  (void)in_sizes; (void)n_in; (void)out_size; (void)ws_size;
  const float* x   = (const float*)d_in[0];
  const float* w   = (const float*)d_in[1];
  const float* cc  = (const float*)d_in[2];
  const float* ws0 = (const float*)d_in[3];
  float* out = (float*)d_out;
  float* ws  = (float*)d_ws;

  hipMemsetAsync(d_ws, 0, (size_t)WS_ZERO_UNITS * 4, stream);
  hipLaunchKernelGGL(prep_kernel,         dim3(288), dim3(256), 0, stream, w, ws);
  hipLaunchKernelGGL(argmin_kernel,       dim3(512), dim3(256), 0, stream, x, out, ws);
  hipLaunchKernelGGL(stats_kernel,        dim3(1),   dim3(256), 0, stream, cc, out, ws);
  hipLaunchKernelGGL(update_quant_kernel, dim3(512), dim3(256), 0, stream, x, ws0, out, ws);
  hipLaunchKernelGGL(final_kernel,        dim3(1),   dim3(64),  0, stream, out, ws);
}